// Round 3
// baseline (14533.795 us; speedup 1.0000x reference)
//
#include <hip/hip_runtime.h>
#include <hip/hip_fp16.h>

#define T_STEPS 500
#define HBUF_STRIDE 40960   // per (g,buf): hi 16384 | lo 16384 | fp8 8192
#define F8_SCALE    32768.0f
#define F8_INV      3.0517578125e-05f   // 2^-15

typedef _Float16 half_t;
typedef __attribute__((ext_vector_type(8))) _Float16 half8;
typedef __attribute__((ext_vector_type(4))) float    f32x4;
typedef unsigned int       u32;
typedef unsigned long long u64;

// Persistent LSTM. grid = 128 x 512 threads (8 waves), 1 block/CU -> co-resident.
//   group g = bid & 15 owns batch rows [16g,16g+16); j = bid>>4 owns hidden
//   slice U0 = j*64 (gate cols {gate*512+U0+u}).
//   W_hh slice in registers as fp16 hi (128 VGPR) + fp8-e4m3 residual*2^15 (64 VGPR).
//   gates = h_hi@W_hi + h_lo@W_hi + 2^-15 * (fp8(h) @ W_lo8)   [fp32 MFMA accum]
//   Cross-block h exchange via L2: plain stores + __threadfence + release flag;
//   readers use agent-scope atomic loads (bypass L1).
// ws: flags[16][32] u32 @ 0 (memset 0); hbuf [16 g][2 buf][40960 B] @ 4096.

__device__ __forceinline__ float sigmoid_fast(float v) {
    return 1.f / (1.f + __expf(-v));
}
__device__ __forceinline__ float tanh_fast(float v) {
    float a = fabsf(v);
    float e = __expf(-2.f * a);
    float t = (1.f - e) / (1.f + e);
    return copysignf(t, v);
}

__global__ __launch_bounds__(512, 2) void lstm_persist(
    const float* __restrict__ x,     const float* __restrict__ w_ih,
    const float* __restrict__ w_hh,  const float* __restrict__ b_ih,
    const float* __restrict__ b_hh,  const float* __restrict__ w_lin,
    const float* __restrict__ b_lin, float* __restrict__ out,
    u32* flags, char* hbase)
{
    __shared__ __align__(16) char stageBuf[40960];   // hi | lo | fp8, linear
    __shared__ float gate_s[4][16][66];
    __shared__ float wb_s[4][64][2];                 // {w_ih, b_ih+b_hh} per (gate,u)
    __shared__ float xbuf[16];

    half8* ldsAhi = (half8*)stageBuf;
    half8* ldsAlo = (half8*)(stageBuf + 16384);
    long*  ldsA8  = (long*)(stageBuf + 32768);

    const int tid = threadIdx.x;
    const int bid = blockIdx.x;
    const int g   = bid & 15;
    const int j   = bid >> 4;
    const int U0  = j * 64;
    const int m0  = g * 16;

    const int wave = tid >> 6, lane = tid & 63;
    const int kg   = lane >> 4, l15 = lane & 15;
    const int gw   = wave >> 1;            // gate 0..3 (i,f,g,o)
    const int usub = (wave & 1) * 32;

    // ---- one-time: W_hh slice -> registers (fp16 hi + fp8 residual) ----
    half8 bw0[16], bw1[16];
    long  b80[16], b81[16];
    {
        const int col0 = gw * 512 + U0 + usub + l15;
        const int col1 = col0 + 16;
#pragma unroll
        for (int ks = 0; ks < 16; ++ks) {
            const float* p0 = w_hh + col0 * 512 + ks * 32 + kg * 8;
            const float* p1 = w_hh + col1 * 512 + ks * 32 + kg * 8;
            float v0[8], v1[8];
            *(float4*)(v0)     = *(const float4*)p0;
            *(float4*)(v0 + 4) = *(const float4*)(p0 + 4);
            *(float4*)(v1)     = *(const float4*)p1;
            *(float4*)(v1 + 4) = *(const float4*)(p1 + 4);
            half8 w0h, w1h; float r0[8], r1[8];
#pragma unroll
            for (int q = 0; q < 8; ++q) {
                half_t a = (half_t)v0[q]; w0h[q] = a; r0[q] = (v0[q] - (float)a) * F8_SCALE;
                half_t b = (half_t)v1[q]; w1h[q] = b; r1[q] = (v1[q] - (float)b) * F8_SCALE;
            }
            bw0[ks] = w0h; bw1[ks] = w1h;
            int lo = __builtin_amdgcn_cvt_pk_fp8_f32(r0[0], r0[1], 0, false);
            lo     = __builtin_amdgcn_cvt_pk_fp8_f32(r0[2], r0[3], lo, true);
            int hi = __builtin_amdgcn_cvt_pk_fp8_f32(r0[4], r0[5], 0, false);
            hi     = __builtin_amdgcn_cvt_pk_fp8_f32(r0[6], r0[7], hi, true);
            b80[ks] = (long)(u32)lo | ((long)hi << 32);
            lo = __builtin_amdgcn_cvt_pk_fp8_f32(r1[0], r1[1], 0, false);
            lo = __builtin_amdgcn_cvt_pk_fp8_f32(r1[2], r1[3], lo, true);
            hi = __builtin_amdgcn_cvt_pk_fp8_f32(r1[4], r1[5], 0, false);
            hi = __builtin_amdgcn_cvt_pk_fp8_f32(r1[6], r1[7], hi, true);
            b81[ks] = (long)(u32)lo | ((long)hi << 32);
        }
    }

    // ---- one-time: pointwise constants -> LDS ----
    if (tid < 256) {
        int gg = tid >> 6, ul = tid & 63;
        int col = gg * 512 + U0 + ul;
        wb_s[gg][ul][0] = w_ih[col];
        wb_s[gg][ul][1] = b_ih[col] + b_hh[col];
    }

    const int pm = tid >> 5;          // local batch row 0..15
    const int pu = (tid & 31) * 2;    // local hidden pair 0..62
    const int kbg = j * 8 + (pu >> 3);                       // global k-block
    const int off_hi = kbg * 256 + pm * 16 + (pu & 7) * 2;   // bytes in hi/lo region
    const int off_8  = kbg * 128 + pm * 8  + (pu & 7);       // bytes in fp8 region

    float c0 = 0.f, c1 = 0.f, h0f = 0.f, h1f = 0.f;
    u32* gflags = flags + g * 32;

    // ---- startup: zero ENTIRE buf[1] region of this group (h_{-1}=0) ----
    {
        u64* z = (u64*)(hbase + (g * 2 + 1) * HBUF_STRIDE);
#pragma unroll
        for (int r = 0; r < 10; ++r) z[r * 512 + tid] = 0ull;
    }
    __threadfence();
    __syncthreads();
    if (tid == 0)
        __hip_atomic_store(&gflags[j], 1u, __ATOMIC_RELEASE, __HIP_MEMORY_SCOPE_AGENT);

    // ---- time loop ----
    for (int t = 0; t < T_STEPS; ++t) {
        const int wb = t & 1, rb = wb ^ 1;

        if (tid < 8) {
            while (__hip_atomic_load(&gflags[tid], __ATOMIC_ACQUIRE,
                                     __HIP_MEMORY_SCOPE_AGENT) < (u32)(t + 1))
                __builtin_amdgcn_s_sleep(1);
        }
        if (tid < 16) xbuf[tid] = x[t * 256 + m0 + tid];
        __syncthreads();

        // stage h_{t-1} tile (40 KB) into LDS; atomic loads bypass stale L1
        {
            const u64* src = (const u64*)(hbase + (g * 2 + rb) * HBUF_STRIDE);
            u64* dst = (u64*)stageBuf;
#pragma unroll
            for (int r = 0; r < 10; ++r)
                dst[r * 512 + tid] = __hip_atomic_load(src + r * 512 + tid,
                                        __ATOMIC_RELAXED, __HIP_MEMORY_SCOPE_AGENT);
        }
        __syncthreads();

        // GEMM: 3-term split precision, B from registers, A from LDS
        f32x4 acc0 = {0.f, 0.f, 0.f, 0.f};
        f32x4 acc1 = {0.f, 0.f, 0.f, 0.f};
        f32x4 c80  = {0.f, 0.f, 0.f, 0.f};
        f32x4 c81  = {0.f, 0.f, 0.f, 0.f};
#pragma unroll
        for (int ks = 0; ks < 16; ++ks) {
            const int ai = (ks * 4 + kg) * 16 + l15;
            half8 ahi = ldsAhi[ai];
            half8 alo = ldsAlo[ai];
            long  a8  = ldsA8[ai];
            acc0 = __builtin_amdgcn_mfma_f32_16x16x32_f16(ahi, bw0[ks], acc0, 0, 0, 0);
            acc1 = __builtin_amdgcn_mfma_f32_16x16x32_f16(ahi, bw1[ks], acc1, 0, 0, 0);
            acc0 = __builtin_amdgcn_mfma_f32_16x16x32_f16(alo, bw0[ks], acc0, 0, 0, 0);
            acc1 = __builtin_amdgcn_mfma_f32_16x16x32_f16(alo, bw1[ks], acc1, 0, 0, 0);
            c80  = __builtin_amdgcn_mfma_f32_16x16x32_fp8_fp8(a8, b80[ks], c80, 0, 0, 0);
            c81  = __builtin_amdgcn_mfma_f32_16x16x32_fp8_fp8(a8, b81[ks], c81, 0, 0, 0);
        }
        // D layout: col = lane&15, row = (lane>>4)*4 + e
#pragma unroll
        for (int e = 0; e < 4; ++e) {
            gate_s[gw][kg * 4 + e][usub + l15]      = acc0[e] + c80[e] * F8_INV;
            gate_s[gw][kg * 4 + e][usub + 16 + l15] = acc1[e] + c81[e] * F8_INV;
        }
        __syncthreads();

        // pointwise: thread owns (pm, pu), (pm, pu+1)
        {
            float xv = xbuf[pm];
            float4 wbi = *(float4*)&wb_s[0][pu][0];
            float4 wbf = *(float4*)&wb_s[1][pu][0];
            float4 wbg = *(float4*)&wb_s[2][pu][0];
            float4 wbo = *(float4*)&wb_s[3][pu][0];
            float si0 = gate_s[0][pm][pu]     + xv * wbi.x + wbi.y;
            float si1 = gate_s[0][pm][pu + 1] + xv * wbi.z + wbi.w;
            float sf0 = gate_s[1][pm][pu]     + xv * wbf.x + wbf.y;
            float sf1 = gate_s[1][pm][pu + 1] + xv * wbf.z + wbf.w;
            float sg0 = gate_s[2][pm][pu]     + xv * wbg.x + wbg.y;
            float sg1 = gate_s[2][pm][pu + 1] + xv * wbg.z + wbg.w;
            float so0 = gate_s[3][pm][pu]     + xv * wbo.x + wbo.y;
            float so1 = gate_s[3][pm][pu + 1] + xv * wbo.z + wbo.w;
            float ii0 = sigmoid_fast(si0), ii1 = sigmoid_fast(si1);
            float ff0 = sigmoid_fast(sf0), ff1 = sigmoid_fast(sf1);
            float gg0 = tanh_fast(sg0),    gg1 = tanh_fast(sg1);
            float oo0 = sigmoid_fast(so0), oo1 = sigmoid_fast(so1);
            c0 = ff0 * c0 + ii0 * gg0;
            c1 = ff1 * c1 + ii1 * gg1;
            h0f = oo0 * tanh_fast(c0);
            h1f = oo1 * tanh_fast(c1);

            char* wrb = hbase + (g * 2 + wb) * HBUF_STRIDE;
            half_t h0h = (half_t)h0f; float h0lo = h0f - (float)h0h;
            half_t h1h = (half_t)h1f; float h1lo = h1f - (float)h1h;
            union { half_t h[2]; u32 u; } pk;
            pk.h[0] = h0h; pk.h[1] = h1h;
            *(u32*)(wrb + off_hi) = pk.u;
            pk.h[0] = (half_t)h0lo; pk.h[1] = (half_t)h1lo;
            *(u32*)(wrb + 16384 + off_hi) = pk.u;
            int p8 = __builtin_amdgcn_cvt_pk_fp8_f32(h0f, h1f, 0, false);
            *(unsigned short*)(wrb + 32768 + off_8) = (unsigned short)p8;
        }
        __threadfence();   // drain h stores to L2 before publishing
        __syncthreads();
        if (tid == 0)
            __hip_atomic_store(&gflags[j], (u32)(t + 2), __ATOMIC_RELEASE,
                               __HIP_MEMORY_SCOPE_AGENT);
    }

    // ---- output: out[b] = w_lin . h_499[b] + b_lin (h in registers) ----
    {
        float partial = h0f * w_lin[U0 + pu] + h1f * w_lin[U0 + pu + 1];
#pragma unroll
        for (int off = 16; off >= 1; off >>= 1)
            partial += __shfl_xor(partial, off, 64);
        if ((lane & 31) == 0) {
            int m = wave * 2 + (lane >> 5);
            float v = partial;
            if (j == 0) v += b_lin[0];
            atomicAdd(out + m0 + m, v);
        }
    }
}

extern "C" void kernel_launch(void* const* d_in, const int* in_sizes, int n_in,
                              void* d_out, int out_size, void* d_ws, size_t ws_size,
                              hipStream_t stream) {
    const float* x     = (const float*)d_in[0];
    const float* w_ih  = (const float*)d_in[1];
    const float* w_hh  = (const float*)d_in[2];
    const float* b_ih  = (const float*)d_in[3];
    const float* b_hh  = (const float*)d_in[4];
    const float* w_lin = (const float*)d_in[5];
    const float* b_lin = (const float*)d_in[6];
    float* out = (float*)d_out;

    u32*  flags = (u32*)d_ws;
    char* hbase = (char*)d_ws + 4096;

    hipMemsetAsync(d_out, 0, out_size * sizeof(float), stream);
    hipMemsetAsync(d_ws, 0, 4096, stream);

    hipLaunchKernelGGL(lstm_persist, dim3(128), dim3(512), 0, stream,
                       x, w_ih, w_hh, b_ih, b_hh, w_lin, b_lin, out, flags, hbase);
}